// Round 1
// baseline (616.373 us; speedup 1.0000x reference)
//
#include <hip/hip_runtime.h>
#include <math.h>

#define GW 38
#define GH 38
#define NA 25
#define NB 512
#define HW (GW * GH)            // 1444
#define S4 (HW / 4)             // 361 float4 per plane
#define CELLS4 (NB * NA * S4)   // 4,620,800 threads
#define BLK 256

struct Meta {
    float gx, gy, gw, gh;
    float tconf, tb0, tb1, tb2, tb3;
    int   best, gi, gj;
};

__device__ __forceinline__ float sigmoidf(float x) {
    return 1.0f / (1.0f + expf(-x));
}

__device__ __forceinline__ float iou_f(float x1, float y1, float w1, float h1,
                                       float x2, float y2, float w2, float h2) {
    float mx = fminf(x1 - w1 * 0.5f, x2 - w2 * 0.5f);
    float Mx = fmaxf(x1 + w1 * 0.5f, x2 + w2 * 0.5f);
    float my = fminf(y1 - h1 * 0.5f, y2 - h2 * 0.5f);
    float My = fmaxf(y1 + h1 * 0.5f, y2 + h2 * 0.5f);
    float cw = w1 + w2 - (Mx - mx);
    float ch = h1 + h2 - (My - my);
    float inter = (cw > 0.0f && ch > 0.0f) ? cw * ch : 0.0f;
    float uni = w1 * h1 + w2 * h2 - inter;
    return inter / uni;
}

// anchors = float32(_BASE) * float32(scale), scale in {0.5,0.75,1.0,1.25,1.5}
__device__ __forceinline__ void anchor_wh(int a, float* aw, float* ah) {
    const float bw[5] = {1.3221f, 3.19275f, 5.05587f, 9.47112f, 11.2364f};
    const float bh[5] = {1.73145f, 4.00944f, 8.09892f, 4.84053f, 10.0071f};
    float s = 0.5f + 0.25f * (float)(a / 5);
    *aw = bw[a % 5] * s;
    *ah = bh[a % 5] * s;
}

__global__ void meta_kernel(const float* __restrict__ pred,
                            const float* __restrict__ target,
                            Meta* __restrict__ metas) {
    int b = blockIdx.x * blockDim.x + threadIdx.x;
    if (b >= NB) return;
    float gx = target[b * 4 + 0] * (float)GW;
    float gy = target[b * 4 + 1] * (float)GH;
    float gw = target[b * 4 + 2] * (float)GW;
    float gh = target[b * 4 + 3] * (float)GH;
    // argmax over anchor IoUs (centered boxes); strict > keeps first max like jnp.argmax
    int best = 0;
    float best_iou = -1.0f;
    for (int a = 0; a < NA; ++a) {
        float aw, ah;
        anchor_wh(a, &aw, &ah);
        float v = iou_f(0.0f, 0.0f, aw, ah, 0.0f, 0.0f, gw, gh);
        if (v > best_iou) { best_iou = v; best = a; }
    }
    int gi = (int)gx;
    int gj = (int)gy;
    float aw, ah;
    anchor_wh(best, &aw, &ah);
    size_t base = (size_t)b * NA * 5 * HW + (size_t)(best * 5) * HW + gj * GW + gi;
    float p0 = pred[base + 0 * HW];
    float p1 = pred[base + 1 * HW];
    float p2 = pred[base + 2 * HW];
    float p3 = pred[base + 3 * HW];
    float pbx = sigmoidf(p0) + (float)gi;
    float pby = sigmoidf(p1) + (float)gj;
    float pbw = expf(p2) * aw;
    float pbh = expf(p3) * ah;
    Meta m;
    m.gx = gx; m.gy = gy; m.gw = gw; m.gh = gh;
    m.tconf = iou_f(pbx, pby, pbw, pbh, gx, gy, gw, gh);
    m.tb0 = gx - (float)gi;
    m.tb1 = gy - (float)gj;
    m.tb2 = logf(gw / aw);
    m.tb3 = logf(gh / ah);
    m.best = best; m.gi = gi; m.gj = gj;
    metas[b] = m;
}

__global__ __launch_bounds__(BLK) void loss_kernel(const float* __restrict__ pred,
                                                   const Meta* __restrict__ metas,
                                                   float* __restrict__ out) {
    unsigned t = blockIdx.x * (unsigned)BLK + threadIdx.x;
    unsigned plane = t / (unsigned)S4;        // b*25 + a
    unsigned s4 = t - plane * (unsigned)S4;   // float4 index inside plane
    unsigned b = plane / (unsigned)NA;
    unsigned a = plane - b * (unsigned)NA;

    Meta m = metas[b];
    float aw, ah;
    anchor_wh((int)a, &aw, &ah);

    // plane (b,a) starts at plane*5*1444 floats; byte offset is 16B-aligned
    const float4* base = (const float4*)(pred + (size_t)plane * 5u * (unsigned)HW);
    float4 q0 = base[s4 + 0u * S4];
    float4 q1 = base[s4 + 1u * S4];
    float4 q2 = base[s4 + 2u * S4];
    float4 q3 = base[s4 + 3u * S4];
    float4 q4 = base[s4 + 4u * S4];
    float r0[4] = {q0.x, q0.y, q0.z, q0.w};
    float r1[4] = {q1.x, q1.y, q1.z, q1.w};
    float r2[4] = {q2.x, q2.y, q2.z, q2.w};
    float r3[4] = {q3.x, q3.y, q3.z, q3.w};
    float r4[4] = {q4.x, q4.y, q4.z, q4.w};

    float acc = 0.0f;
#pragma unroll
    for (int k = 0; k < 4; ++k) {
        unsigned s = s4 * 4u + (unsigned)k;
        unsigned j = s / (unsigned)GW;
        unsigned i = s - j * (unsigned)GW;
        float tx = sigmoidf(r0[k]);
        float ty = sigmoidf(r1[k]);
        float tw = r2[k];
        float th = r3[k];
        float conf = sigmoidf(r4[k]);
        float bx = tx + (float)i;
        float by = ty + (float)j;
        float bw = expf(tw) * aw;
        float bh = expf(th) * ah;
        float iou = iou_f(bx, by, bw, bh, m.gx, m.gy, m.gw, m.gh);
        bool obj = (a == (unsigned)m.best) && (j == (unsigned)m.gj) && (i == (unsigned)m.gi);
        // conf_mask: set 0/1 by sil-thresh, overwrite 5 at object cell, then sqrt
        float cm = obj ? 2.23606797749979f : ((iou > 0.6f) ? 0.0f : 1.0f);
        float tb0 = obj ? m.tb0 : 0.5f;
        float tb1 = obj ? m.tb1 : 0.5f;
        float tb2 = obj ? m.tb2 : 0.0f;
        float tb3 = obj ? m.tb3 : 0.0f;
        float tc  = obj ? m.tconf : 0.0f;
        float dx = tx - tb0;
        float dy = ty - tb1;
        float dw = tw - tb2;
        float dh = th - tb3;
        float dc = cm * conf - cm * tc;
        acc += dx * dx + dy * dy + dw * dw + dh * dh + dc * dc;
    }

    // wave64 shuffle reduce, then cross-wave via LDS
    for (int off = 32; off > 0; off >>= 1)
        acc += __shfl_down(acc, off, 64);
    __shared__ float sm[BLK / 64];
    int lane = (int)(threadIdx.x & 63u);
    int wv = (int)(threadIdx.x >> 6u);
    if (lane == 0) sm[wv] = acc;
    __syncthreads();
    if (threadIdx.x == 0) {
        float s = 0.0f;
        for (int w = 0; w < BLK / 64; ++w) s += sm[w];
        atomicAdd(out, 0.5f * s);  // every loss term carries the /2
    }
}

extern "C" void kernel_launch(void* const* d_in, const int* in_sizes, int n_in,
                              void* d_out, int out_size, void* d_ws, size_t ws_size,
                              hipStream_t stream) {
    const float* pred = (const float*)d_in[0];
    const float* target = (const float*)d_in[1];
    float* out = (float*)d_out;
    Meta* metas = (Meta*)d_ws;

    // d_out is poisoned 0xAA before every timed launch — zero it for the atomics
    hipMemsetAsync(d_out, 0, (size_t)out_size * sizeof(float), stream);

    meta_kernel<<<(NB + BLK - 1) / BLK, BLK, 0, stream>>>(pred, target, metas);
    loss_kernel<<<CELLS4 / BLK, BLK, 0, stream>>>(pred, metas, out);
}

// Round 2
// 508.483 us; speedup vs baseline: 1.2122x; 1.2122x over previous
//
#include <hip/hip_runtime.h>
#include <math.h>

#define GW 38
#define GH 38
#define NA 25
#define NB 512
#define HW (GW * GH)              // 1444
#define S4 (HW / 4)               // 361 float4 per channel-plane
#define PLANES (NB * NA)          // 12800 (b,a) planes
#define HALF_PLANES (PLANES / 2)  // 6400 → +6400 planes == +256 batches
#define T_TOTAL (HALF_PLANES * S4)  // 2,310,400 threads
#define BLK 256

struct Meta {
    float gxlo, gxhi, gylo, gyhi;  // gx -/+ gw/2, gy -/+ gh/2
    float gw, gh, area;            // gw*gh
    float tconf, tb0, tb1, tb2, tb3;
    int   best, cell;              // cell = gj*38 + gi
};

__device__ __forceinline__ float fast_rcp(float x) { return __builtin_amdgcn_rcpf(x); }
__device__ __forceinline__ float fast_exp(float x) { return __expf(x); }          // v_exp_f32
__device__ __forceinline__ float fast_sig(float x) { return fast_rcp(1.0f + fast_exp(-x)); }

__device__ __forceinline__ float iou_precise(float x1, float y1, float w1, float h1,
                                             float x2, float y2, float w2, float h2) {
    float mx = fminf(x1 - w1 * 0.5f, x2 - w2 * 0.5f);
    float Mx = fmaxf(x1 + w1 * 0.5f, x2 + w2 * 0.5f);
    float my = fminf(y1 - h1 * 0.5f, y2 - h2 * 0.5f);
    float My = fmaxf(y1 + h1 * 0.5f, y2 + h2 * 0.5f);
    float cw = w1 + w2 - (Mx - mx);
    float ch = h1 + h2 - (My - my);
    float inter = (cw > 0.0f && ch > 0.0f) ? cw * ch : 0.0f;
    float uni = w1 * h1 + w2 * h2 - inter;
    return inter / uni;
}

// anchors = float32(_BASE) * float32(scale), scale in {0.5,0.75,1.0,1.25,1.5}
__device__ __forceinline__ void anchor_wh(int a, float* aw, float* ah) {
    const float bw[5] = {1.3221f, 3.19275f, 5.05587f, 9.47112f, 11.2364f};
    const float bh[5] = {1.73145f, 4.00944f, 8.09892f, 4.84053f, 10.0071f};
    float s = 0.5f + 0.25f * (float)(a / 5);
    *aw = bw[a % 5] * s;
    *ah = bh[a % 5] * s;
}

__global__ void meta_kernel(const float* __restrict__ pred,
                            const float* __restrict__ target,
                            Meta* __restrict__ metas) {
    int b = blockIdx.x * blockDim.x + threadIdx.x;
    if (b >= NB) return;
    float gx = target[b * 4 + 0] * (float)GW;
    float gy = target[b * 4 + 1] * (float)GH;
    float gw = target[b * 4 + 2] * (float)GW;
    float gh = target[b * 4 + 3] * (float)GH;
    int best = 0;
    float best_iou = -1.0f;
    for (int a = 0; a < NA; ++a) {
        float aw, ah;
        anchor_wh(a, &aw, &ah);
        float v = iou_precise(0.0f, 0.0f, aw, ah, 0.0f, 0.0f, gw, gh);
        if (v > best_iou) { best_iou = v; best = a; }
    }
    int gi = (int)gx;
    int gj = (int)gy;
    float aw, ah;
    anchor_wh(best, &aw, &ah);
    size_t base = (size_t)b * NA * 5 * HW + (size_t)(best * 5) * HW + gj * GW + gi;
    float p0 = pred[base + 0 * HW];
    float p1 = pred[base + 1 * HW];
    float p2 = pred[base + 2 * HW];
    float p3 = pred[base + 3 * HW];
    float pbx = 1.0f / (1.0f + expf(-p0)) + (float)gi;   // precise path (512 cells only)
    float pby = 1.0f / (1.0f + expf(-p1)) + (float)gj;
    float pbw = expf(p2) * aw;
    float pbh = expf(p3) * ah;
    Meta m;
    m.gxlo = gx - gw * 0.5f; m.gxhi = gx + gw * 0.5f;
    m.gylo = gy - gh * 0.5f; m.gyhi = gy + gh * 0.5f;
    m.gw = gw; m.gh = gh; m.area = gw * gh;
    m.tconf = iou_precise(pbx, pby, pbw, pbh, gx, gy, gw, gh);
    m.tb0 = gx - (float)gi;
    m.tb1 = gy - (float)gj;
    m.tb2 = logf(gw / aw);
    m.tb3 = logf(gh / ah);
    m.best = best;
    m.cell = gj * GW + gi;
    metas[b] = m;
}

// per-cell loss: coords (dx²+dy²+dw²+dh²) + masked conf term
__device__ __forceinline__ float cell_loss(float p0, float p1, float p2, float p3, float p4,
                                           float fi, float fj, bool obj,
                                           const Meta& m, float aw, float ah) {
    float tx = fast_sig(p0);
    float ty = fast_sig(p1);
    float conf = fast_sig(p4);
    float bw = fast_exp(p2) * aw;
    float bh = fast_exp(p3) * ah;
    float bx = tx + fi;
    float by = ty + fj;
    float mx = fminf(bx - bw * 0.5f, m.gxlo);
    float Mx = fmaxf(bx + bw * 0.5f, m.gxhi);
    float my = fminf(by - bh * 0.5f, m.gylo);
    float My = fmaxf(by + bh * 0.5f, m.gyhi);
    float cw = bw + m.gw - (Mx - mx);
    float ch = bh + m.gh - (My - my);
    float inter = (cw > 0.0f && ch > 0.0f) ? cw * ch : 0.0f;
    float uni = bw * bh + m.area - inter;
    float iou = inter * fast_rcp(uni);
    float cm = obj ? 2.23606797749979f : ((iou > 0.6f) ? 0.0f : 1.0f);  // sqrt(5)/0/1
    float dx = tx - (obj ? m.tb0 : 0.5f);
    float dy = ty - (obj ? m.tb1 : 0.5f);
    float dw = p2 - (obj ? m.tb2 : 0.0f);
    float dh = p3 - (obj ? m.tb3 : 0.0f);
    float dc = cm * (conf - (obj ? m.tconf : 0.0f));
    return dx * dx + dy * dy + dw * dw + dh * dh + dc * dc;
}

__global__ __launch_bounds__(BLK) void loss_kernel(const float* __restrict__ pred,
                                                   const Meta* __restrict__ metas,
                                                   float* __restrict__ out) {
    unsigned t = blockIdx.x * (unsigned)BLK + threadIdx.x;
    unsigned plane = t / (unsigned)S4;        // b*25 + a, b in [0,256)
    unsigned s4 = t - plane * (unsigned)S4;
    unsigned b = plane / (unsigned)NA;
    unsigned a = plane - b * (unsigned)NA;

    // group 0: (b, a); group 1: (b+256, a) — same s4, same i/j, same anchor
    const float4* base0 = (const float4*)(pred + (size_t)plane * 5u * (unsigned)HW);
    const float4* base1 = base0 + (size_t)HALF_PLANES * 5u * (unsigned)S4;

    // issue all 10 loads before any dependent compute
    float4 q0 = base0[s4 + 0u * S4];
    float4 q1 = base0[s4 + 1u * S4];
    float4 q2 = base0[s4 + 2u * S4];
    float4 q3 = base0[s4 + 3u * S4];
    float4 q4 = base0[s4 + 4u * S4];
    float4 r0 = base1[s4 + 0u * S4];
    float4 r1 = base1[s4 + 1u * S4];
    float4 r2 = base1[s4 + 2u * S4];
    float4 r3 = base1[s4 + 3u * S4];
    float4 r4 = base1[s4 + 4u * S4];

    Meta m0 = metas[b];
    Meta m1 = metas[b + 256];
    float aw, ah;
    anchor_wh((int)a, &aw, &ah);
    bool aok0 = (a == (unsigned)m0.best);
    bool aok1 = (a == (unsigned)m1.best);

    float qa[5][4] = {{q0.x, q0.y, q0.z, q0.w}, {q1.x, q1.y, q1.z, q1.w},
                      {q2.x, q2.y, q2.z, q2.w}, {q3.x, q3.y, q3.z, q3.w},
                      {q4.x, q4.y, q4.z, q4.w}};
    float ra[5][4] = {{r0.x, r0.y, r0.z, r0.w}, {r1.x, r1.y, r1.z, r1.w},
                      {r2.x, r2.y, r2.z, r2.w}, {r3.x, r3.y, r3.z, r3.w},
                      {r4.x, r4.y, r4.z, r4.w}};

    float acc = 0.0f;
#pragma unroll
    for (int k = 0; k < 4; ++k) {
        unsigned s = s4 * 4u + (unsigned)k;
        unsigned j = s / (unsigned)GW;
        unsigned i = s - j * (unsigned)GW;
        float fi = (float)i, fj = (float)j;
        bool obj0 = aok0 && (s == (unsigned)m0.cell);
        bool obj1 = aok1 && (s == (unsigned)m1.cell);
        acc += cell_loss(qa[0][k], qa[1][k], qa[2][k], qa[3][k], qa[4][k], fi, fj, obj0, m0, aw, ah);
        acc += cell_loss(ra[0][k], ra[1][k], ra[2][k], ra[3][k], ra[4][k], fi, fj, obj1, m1, aw, ah);
    }

    // wave64 shuffle reduce → LDS across 4 waves → one atomic per block
    for (int off = 32; off > 0; off >>= 1)
        acc += __shfl_down(acc, off, 64);
    __shared__ float sm[BLK / 64];
    int lane = (int)(threadIdx.x & 63u);
    int wv = (int)(threadIdx.x >> 6u);
    if (lane == 0) sm[wv] = acc;
    __syncthreads();
    if (threadIdx.x == 0) {
        float s = sm[0] + sm[1] + sm[2] + sm[3];
        atomicAdd(out, 0.5f * s);
    }
}

extern "C" void kernel_launch(void* const* d_in, const int* in_sizes, int n_in,
                              void* d_out, int out_size, void* d_ws, size_t ws_size,
                              hipStream_t stream) {
    const float* pred = (const float*)d_in[0];
    const float* target = (const float*)d_in[1];
    float* out = (float*)d_out;
    Meta* metas = (Meta*)d_ws;

    hipMemsetAsync(d_out, 0, (size_t)out_size * sizeof(float), stream);
    meta_kernel<<<(NB + BLK - 1) / BLK, BLK, 0, stream>>>(pred, target, metas);
    loss_kernel<<<T_TOTAL / BLK, BLK, 0, stream>>>(pred, metas, out);
}